// Round 2
// baseline (50.723 us; speedup 1.0000x reference)
//
#include <hip/hip_runtime.h>

// Dynamic 3x3 softmax-weighted conv, reflect padding.
// x: (4, 64, 256, 256) f32, kernel: (4, 9, 256, 256) f32, out: (4, 64, 256, 256) f32
// out[b,c,h,w] = sum_{dy,dx} softmax_j(kernel[b,:,h,w])[dy*3+dx] * x_reflect[b,c,h+dy-1,w+dx-1]

constexpr int BATCH = 4;
constexpr int CHAN  = 64;
constexpr int HH    = 256;
constexpr int WW    = 256;
constexpr int CG    = 8;   // channels per block (softmax amortized over these)
constexpr int RPB   = 4;   // rows per block

__global__ __launch_bounds__(256) void dynconv_kernel(
    const float* __restrict__ x,
    const float* __restrict__ ker,
    float* __restrict__ out)
{
    const int t  = threadIdx.x;
    const int rb = t >> 6;          // row within band, 0..3
    const int wq = t & 63;          // float4 slot, 0..63
    const int w0 = wq * 4;

    const int hband = blockIdx.x;   // 0..63
    const int cg    = blockIdx.y;   // 0..7
    const int b     = blockIdx.z;   // 0..3
    const int h     = hband * RPB + rb;

    // ---- softmax over the 9 taps, for 4 pixels, in registers ----
    float kv[9][4];
    const long kbase = (((long)b * 9) * HH + h) * WW + w0;
    #pragma unroll
    for (int j = 0; j < 9; ++j) {
        const float4 v = *reinterpret_cast<const float4*>(ker + kbase + (long)j * HH * WW);
        kv[j][0] = v.x; kv[j][1] = v.y; kv[j][2] = v.z; kv[j][3] = v.w;
    }
    #pragma unroll
    for (int p = 0; p < 4; ++p) {
        float m = kv[0][p];
        #pragma unroll
        for (int j = 1; j < 9; ++j) m = fmaxf(m, kv[j][p]);
        float s = 0.f;
        #pragma unroll
        for (int j = 0; j < 9; ++j) { kv[j][p] = __expf(kv[j][p] - m); s += kv[j][p]; }
        const float inv = 1.0f / s;
        #pragma unroll
        for (int j = 0; j < 9; ++j) kv[j][p] *= inv;
    }

    // ---- reflect indices (pad=1, mode='reflect': idx -1 -> 1, idx N -> N-2) ----
    const int hm = (h == 0)      ? 1      : h - 1;
    const int hp = (h == HH - 1) ? HH - 2 : h + 1;
    const int wl = (w0 == 0)       ? 1      : w0 - 1;   // x index for w0-1
    const int wr = (w0 + 4 == WW)  ? WW - 2 : w0 + 4;   // x index for w0+4
    const int rows[3] = { hm, h, hp };

    // ---- apply to CG channels ----
    #pragma unroll 1
    for (int i = 0; i < CG; ++i) {
        const int c = cg * CG + i;
        const long xbase = (((long)b * CHAN + c) * HH) * WW;
        float acc0 = 0.f, acc1 = 0.f, acc2 = 0.f, acc3 = 0.f;
        #pragma unroll
        for (int r = 0; r < 3; ++r) {
            const long rbase = xbase + (long)rows[r] * WW;
            float vals[6];
            const float4 v = *reinterpret_cast<const float4*>(x + rbase + w0);
            vals[0] = x[rbase + wl];
            vals[1] = v.x; vals[2] = v.y; vals[3] = v.z; vals[4] = v.w;
            vals[5] = x[rbase + wr];
            #pragma unroll
            for (int dx = 0; dx < 3; ++dx) {
                const int j = r * 3 + dx;
                acc0 = fmaf(kv[j][0], vals[0 + dx], acc0);
                acc1 = fmaf(kv[j][1], vals[1 + dx], acc1);
                acc2 = fmaf(kv[j][2], vals[2 + dx], acc2);
                acc3 = fmaf(kv[j][3], vals[3 + dx], acc3);
            }
        }
        float4 o; o.x = acc0; o.y = acc1; o.z = acc2; o.w = acc3;
        *reinterpret_cast<float4*>(out + xbase + (long)h * WW + w0) = o;
    }
}

extern "C" void kernel_launch(void* const* d_in, const int* in_sizes, int n_in,
                              void* d_out, int out_size, void* d_ws, size_t ws_size,
                              hipStream_t stream) {
    const float* x   = (const float*)d_in[0];
    const float* ker = (const float*)d_in[1];
    float* out = (float*)d_out;

    dim3 grid(HH / RPB, CHAN / CG, BATCH);  // (64, 8, 4)
    dim3 block(256);
    dynconv_kernel<<<grid, block, 0, stream>>>(x, ker, out);
}

// Round 3
// 31.965 us; speedup vs baseline: 1.5868x; 1.5868x over previous
//
#include <hip/hip_runtime.h>

// Dynamic 3x3 softmax-weighted conv, reflect padding.
// x: (4, 64, 256, 256) f32, kernel: (4, 9, 256, 256) f32, out: (4, 64, 256, 256) f32
// out[b,c,h,w] = sum_{dy,dx} softmax_j(kernel[b,:,h,w])[dy*3+dx] * x_reflect[b,c,h+dy-1,w+dx-1]

constexpr int BATCH = 4;
constexpr int CHAN  = 64;
constexpr int HH    = 256;
constexpr int WW    = 256;
constexpr int CG    = 8;   // channels per block (softmax amortized over these)
constexpr int RPB   = 4;   // rows per block (one wave per row)

__global__ __launch_bounds__(256) void dynconv_kernel(
    const float* __restrict__ x,
    const float* __restrict__ ker,
    float* __restrict__ out)
{
    const int t  = threadIdx.x;
    const int rb = t >> 6;          // row within band = wave id, 0..3
    const int wq = t & 63;          // lane = float4 slot, 0..63
    const int w0 = wq * 4;

    const int hband = blockIdx.x;   // 0..63
    const int cg    = blockIdx.y;   // 0..7
    const int b     = blockIdx.z;   // 0..3
    const int h     = hband * RPB + rb;

    // ---- softmax over the 9 taps, for 4 pixels, in registers ----
    float kv[9][4];
    const long kbase = (((long)b * 9) * HH + h) * WW + w0;
    #pragma unroll
    for (int j = 0; j < 9; ++j) {
        const float4 v = *reinterpret_cast<const float4*>(ker + kbase + (long)j * HH * WW);
        kv[j][0] = v.x; kv[j][1] = v.y; kv[j][2] = v.z; kv[j][3] = v.w;
    }
    #pragma unroll
    for (int p = 0; p < 4; ++p) {
        float m = kv[0][p];
        #pragma unroll
        for (int j = 1; j < 9; ++j) m = fmaxf(m, kv[j][p]);
        float s = 0.f;
        #pragma unroll
        for (int j = 0; j < 9; ++j) { kv[j][p] = __expf(kv[j][p] - m); s += kv[j][p]; }
        const float inv = 1.0f / s;
        #pragma unroll
        for (int j = 0; j < 9; ++j) kv[j][p] *= inv;
    }

    // ---- reflect row indices (pad=1, 'reflect': -1 -> 1, N -> N-2) ----
    const int hm = (h == 0)      ? 1      : h - 1;
    const int hp = (h == HH - 1) ? HH - 2 : h + 1;
    const int rows[3] = { hm, h, hp };

    // ---- apply to CG channels; halo via cross-lane shuffle (no edge loads) ----
    #pragma unroll 4
    for (int i = 0; i < CG; ++i) {
        const int c = cg * CG + i;
        const long xbase = (((long)b * CHAN + c) * HH) * WW;
        float acc0 = 0.f, acc1 = 0.f, acc2 = 0.f, acc3 = 0.f;
        #pragma unroll
        for (int r = 0; r < 3; ++r) {
            const long rbase = xbase + (long)rows[r] * WW;
            const float4 v = *reinterpret_cast<const float4*>(x + rbase + w0);
            // left halo: lane-1's v.w; lane 0 reflects x[-1] -> x[1] = own v.y
            float lft = __shfl_up(v.w, 1);
            if (wq == 0)  lft = v.y;
            // right halo: lane+1's v.x; lane 63 reflects x[256] -> x[254] = own v.z
            float rgt = __shfl_down(v.x, 1);
            if (wq == 63) rgt = v.z;
            const float vals[6] = { lft, v.x, v.y, v.z, v.w, rgt };
            #pragma unroll
            for (int dx = 0; dx < 3; ++dx) {
                const int j = r * 3 + dx;
                acc0 = fmaf(kv[j][0], vals[0 + dx], acc0);
                acc1 = fmaf(kv[j][1], vals[1 + dx], acc1);
                acc2 = fmaf(kv[j][2], vals[2 + dx], acc2);
                acc3 = fmaf(kv[j][3], vals[3 + dx], acc3);
            }
        }
        float4 o; o.x = acc0; o.y = acc1; o.z = acc2; o.w = acc3;
        *reinterpret_cast<float4*>(out + xbase + (long)h * WW + w0) = o;
    }
}

extern "C" void kernel_launch(void* const* d_in, const int* in_sizes, int n_in,
                              void* d_out, int out_size, void* d_ws, size_t ws_size,
                              hipStream_t stream) {
    const float* x   = (const float*)d_in[0];
    const float* ker = (const float*)d_in[1];
    float* out = (float*)d_out;

    dim3 grid(HH / RPB, CHAN / CG, BATCH);  // (64, 8, 4)
    dim3 block(256);
    dynconv_kernel<<<grid, block, 0, stream>>>(x, ker, out);
}